// Round 4
// baseline (430.985 us; speedup 1.0000x reference)
//
#include <hip/hip_runtime.h>
#include <stdint.h>

// ---------------------------------------------------------------------------
// Phi3 attention block: QKV GEMM -> RoPE -> flash attn (causal, GQA) -> O GEMM
// B=2, S=2048, HID=2048, Hq=32, Hkv=8, D=64. fp32 in/out, bf16 MFMA inside.
// Round 4: (a) GEMMs -> 256x256 8-phase template (BK=64, 8 waves, st_16x32
// LDS swizzle, counted vmcnt, raw barriers, setprio); (b) attn VALU diet:
// raw v_exp_f32, LDS-based P exchange (no bpermutes), double-buffered K/V
// staging with counted vmcnt(4).
// ---------------------------------------------------------------------------

typedef unsigned short u16;
typedef __bf16 bf16x8 __attribute__((ext_vector_type(8)));
typedef float f32x4 __attribute__((ext_vector_type(4)));
typedef unsigned short u16x8 __attribute__((ext_vector_type(8)));

__device__ __forceinline__ u16 f2bf(float f) {
  unsigned int u = __float_as_uint(f);
  u += 0x7fffu + ((u >> 16) & 1u);   // RNE
  return (u16)(u >> 16);
}

__device__ __forceinline__ unsigned cvt_pk_bf16(float lo, float hi) {
  unsigned r;
  asm("v_cvt_pk_bf16_f32 %0, %1, %2" : "=v"(r) : "v"(lo), "v"(hi));
  return r;
}

__device__ __forceinline__ float fexp2(float x) {
  float r;
  asm("v_exp_f32 %0, %1" : "=v"(r) : "v"(x));
  return r;
}

__device__ __forceinline__ void gload_lds16(const void* g, void* l) {
  __builtin_amdgcn_global_load_lds((const __attribute__((address_space(1))) void*)g,
                                   (__attribute__((address_space(3))) void*)l, 16, 0, 0);
}

// --------------------------- fp32 -> bf16 flat copy -------------------------
__global__ __launch_bounds__(256) void conv_bf16_kernel(const float* __restrict__ in,
                                                        u16* __restrict__ out, int n8) {
  int i = blockIdx.x * 256 + threadIdx.x;
  int stride = gridDim.x * 256;
  for (; i < n8; i += stride) {
    const float4* p = (const float4*)in + (size_t)i * 2;
    float4 a = p[0], b = p[1];
    u16x8 o;
    o[0] = f2bf(a.x); o[1] = f2bf(a.y); o[2] = f2bf(a.z); o[3] = f2bf(a.w);
    o[4] = f2bf(b.x); o[5] = f2bf(b.y); o[6] = f2bf(b.z); o[7] = f2bf(b.w);
    *(u16x8*)(out + (size_t)i * 8) = o;
  }
}

// --------------------- fp32 [R][C] -> bf16 transposed [C][R] ----------------
__global__ __launch_bounds__(256) void wtrans_kernel(const float* __restrict__ in,
                                                     u16* __restrict__ out, int R, int C) {
  __shared__ float tile[32][33];
  int tx = threadIdx.x & 31, ty = threadIdx.x >> 5;   // 32x8
  int col = blockIdx.x * 32 + tx;
  for (int j = ty; j < 32; j += 8)
    tile[j][tx] = in[(size_t)(blockIdx.y * 32 + j) * C + col];
  __syncthreads();
  int ocol = blockIdx.y * 32 + tx;                    // out col = in row
  for (int j = ty; j < 32; j += 8)
    out[(size_t)(blockIdx.x * 32 + j) * R + ocol] = f2bf(tile[tx][j]);
}

// ----------------------------- cos/sin tables -------------------------------
__global__ __launch_bounds__(256) void rope_table_kernel(float* __restrict__ cost,
                                                         float* __restrict__ sint) {
  int idx = blockIdx.x * 256 + threadIdx.x;           // 2048*32
  if (idx >= 2048 * 32) return;
  int p = idx >> 5, i = idx & 31;
  float invf = powf(10000.f, -(float)i / 32.f);
  float ang = (float)p * invf;
  cost[idx] = cosf(ang);
  sint[idx] = sinf(ang);
}

// ------------------- 256x256 8-phase bf16 GEMM, B transposed ----------------
// C[M][N] f32 = A[M][K] * Bt[N][K]^T. BK=64, 512 thr = 8 waves (2M x 4N),
// per-wave 128x64 out (8x4 frags). LDS 128KB: 2 bufs x (A 32KB + B 32KB),
// st_16x32 swizzle (byte ^= ((byte>>9)&1)<<5) with pre-swizzled global src.
// Counted vmcnt(8) (1-tile prefetch), raw barriers, 4 phases x 16 MFMA.
__global__ __launch_bounds__(512) void gemm256_kernel(const u16* __restrict__ A,
                                                      const u16* __restrict__ Bt,
                                                      float* __restrict__ C,
                                                      int M, int N, int K) {
  __shared__ __align__(16) char lds[131072];
  const int tid = threadIdx.x;
  const int lane = tid & 63;
  const int w = tid >> 6;
  const int wm = w >> 2, wn = w & 3;

  // XCD-aware bijective block swizzle (nwg % 8 == 0 for all our grids)
  const int nwg = gridDim.x * gridDim.y;
  const int flat = blockIdx.y * gridDim.x + blockIdx.x;
  const int cpx = nwg >> 3;
  const int swb = (flat & 7) * cpx + (flat >> 3);
  const int bx = swb % gridDim.x, by = swb / gridDim.x;
  const int brow = by * 256, bcol = bx * 256;

  const int nt = K >> 6;
  f32x4 acc[8][4] = {};

  auto stage_tile = [&](int kt, int buf) {
    char* ab = lds + buf * 65536;
    char* bb = ab + 32768;
#pragma unroll
    for (int hf = 0; hf < 2; ++hf)
#pragma unroll
      for (int i = 0; i < 2; ++i) {
        int P = (w * 2 + i) * 1024 + lane * 16;
        int L = P ^ (((P >> 9) & 1) << 5);
        int r = L >> 7, c = (L & 127) >> 1;
        gload_lds16(A + (size_t)(brow + hf * 128 + r) * K + kt + c,
                    ab + hf * 16384 + (w * 2 + i) * 1024);
      }
#pragma unroll
    for (int hf = 0; hf < 2; ++hf)
#pragma unroll
      for (int i = 0; i < 2; ++i) {
        int P = (w * 2 + i) * 1024 + lane * 16;
        int L = P ^ (((P >> 9) & 1) << 5);
        int r = L >> 7, c = (L & 127) >> 1;
        gload_lds16(Bt + (size_t)(bcol + hf * 128 + r) * K + kt + c,
                    bb + hf * 16384 + (w * 2 + i) * 1024);
      }
  };

  stage_tile(0, 0);

  for (int t = 0; t < nt; ++t) {
    const int cur = t & 1;
    const char* ah = lds + cur * 65536 + wm * 16384;
    const char* bh = lds + cur * 65536 + 32768 + (wn >> 1) * 16384;
    const int rb = (wn & 1) * 64;

    if (t + 1 < nt) {
      stage_tile((t + 1) << 6, cur ^ 1);
      asm volatile("s_waitcnt vmcnt(8)" ::: "memory");
    } else {
      asm volatile("s_waitcnt vmcnt(0)" ::: "memory");
    }
    __builtin_amdgcn_s_barrier();
    asm volatile("" ::: "memory");   // keep LDS reads below the barrier

#pragma unroll
    for (int p = 0; p < 4; ++p) {
      bf16x8 af[2][2], bfr[4][2];
#pragma unroll
      for (int i = 0; i < 2; ++i)
#pragma unroll
        for (int kk = 0; kk < 2; ++kk) {
          int lin = ((p * 2 + i) * 16 + (lane & 15)) * 128 + kk * 64 + (lane >> 4) * 16;
          af[i][kk] = *(const bf16x8*)(ah + (lin ^ (((lin >> 9) & 1) << 5)));
        }
#pragma unroll
      for (int fn = 0; fn < 4; ++fn)
#pragma unroll
        for (int kk = 0; kk < 2; ++kk) {
          int lin = (rb + fn * 16 + (lane & 15)) * 128 + kk * 64 + (lane >> 4) * 16;
          bfr[fn][kk] = *(const bf16x8*)(bh + (lin ^ (((lin >> 9) & 1) << 5)));
        }
      __builtin_amdgcn_s_barrier();
      __builtin_amdgcn_s_setprio(1);
#pragma unroll
      for (int i = 0; i < 2; ++i)
#pragma unroll
        for (int fn = 0; fn < 4; ++fn)
#pragma unroll
          for (int kk = 0; kk < 2; ++kk)
            acc[p * 2 + i][fn] = __builtin_amdgcn_mfma_f32_16x16x32_bf16(
                af[i][kk], bfr[fn][kk], acc[p * 2 + i][fn], 0, 0, 0);
      __builtin_amdgcn_s_setprio(0);
      __builtin_amdgcn_s_barrier();
    }
  }

#pragma unroll
  for (int fm = 0; fm < 8; ++fm) {
    int row0 = brow + wm * 128 + fm * 16 + (lane >> 4) * 4;
#pragma unroll
    for (int fn = 0; fn < 4; ++fn) {
      int col = bcol + wn * 64 + fn * 16 + (lane & 15);
#pragma unroll
      for (int j = 0; j < 4; ++j)
        C[(size_t)(row0 + j) * N + col] = acc[fm][fn][j];
    }
  }
}

// ------------------- RoPE + scatter q/k into head-major bf16 ----------------
// qkv fp32 [4096][3072] -> Q bf16 [B,32,S,64] (scaled by log2e/8), K bf16 [B,8,S,64]
__global__ __launch_bounds__(256) void rope_scatter_kernel(const float* __restrict__ qkv,
                                                           const int* __restrict__ pos_ids,
                                                           const float* __restrict__ cost,
                                                           const float* __restrict__ sint,
                                                           u16* __restrict__ Qo,
                                                           u16* __restrict__ Ko) {
  int t = blockIdx.x;                 // token 0..4095
  int b = t >> 11, s = t & 2047;
  int pos = pos_ids[t];
  const float* row = qkv + (size_t)t * 3072;
  int tid = threadIdx.x;
  const float QSCALE = 0.125f * 1.44269504088896340736f;  // 1/sqrt(64) * log2(e)

  for (int idx = tid; idx < 1024; idx += 256) {
    int hh = idx >> 5, i = idx & 31;
    float x1 = row[hh * 64 + i], x2 = row[hh * 64 + i + 32];
    float c = cost[pos * 32 + i], sn = sint[pos * 32 + i];
    float o1 = (x1 * c - x2 * sn) * QSCALE;
    float o2 = (x2 * c + x1 * sn) * QSCALE;
    size_t base = ((size_t)(b * 32 + hh) * 2048 + s) * 64;
    Qo[base + i] = f2bf(o1);
    Qo[base + i + 32] = f2bf(o2);
  }
  {
    int hh = tid >> 5, i = tid & 31;
    float x1 = row[2048 + hh * 64 + i], x2 = row[2048 + hh * 64 + i + 32];
    float c = cost[pos * 32 + i], sn = sint[pos * 32 + i];
    float o1 = x1 * c - x2 * sn;
    float o2 = x2 * c + x1 * sn;
    size_t base = ((size_t)(b * 8 + hh) * 2048 + s) * 64;
    Ko[base + i] = f2bf(o1);
    Ko[base + i + 32] = f2bf(o2);
  }
}

// ---------------- V: qkv fp32 cols [2560,3072) -> Vt bf16 [B,8,64,S] --------
__global__ __launch_bounds__(256) void vtrans_kernel(const float* __restrict__ qkv,
                                                     u16* __restrict__ Vt) {
  __shared__ float tile[64][65];
  int b = blockIdx.x >> 3, hv = blockIdx.x & 7;
  int s0 = blockIdx.y * 64;
  int tid = threadIdx.x;
  for (int idx = tid; idx < 4096; idx += 256) {
    int tok = idx >> 6, c = idx & 63;
    tile[tok][c] = qkv[(size_t)(b * 2048 + s0 + tok) * 3072 + 2560 + hv * 64 + c];
  }
  __syncthreads();
  size_t obase = (size_t)(b * 8 + hv) * 64 * 2048;
  for (int idx = tid; idx < 4096; idx += 256) {
    int d = idx >> 6, si = idx & 63;
    Vt[obase + (size_t)d * 2048 + s0 + si] = f2bf(tile[si][d]);
  }
}

// ------------------------------- flash attention ----------------------------
// grid (B*H=64, 16 pairs). Block = 4 waves; q-tiles {pair, 31-pair} -> 33
// balanced iters. Swapped QK^T (S^T: lane&15 = q). Double-buffered K/V LDS
// with counted vmcnt(4); per-wave swizzled LDS P-exchange; raw v_exp_f32.
__global__ __launch_bounds__(256) void attn_kernel(const u16* __restrict__ Q,
                                                   const u16* __restrict__ Kk,
                                                   const u16* __restrict__ Vt,
                                                   u16* __restrict__ O) {
  __shared__ __align__(16) u16 lds_k[2][64 * 64];
  __shared__ __align__(16) u16 lds_v[2][64 * 64];
  __shared__ __align__(16) u16 lds_p[4][1024];   // per-wave 2KB, 16B-slot swizzled

  const int tid = threadIdx.x;
  const int lane = tid & 63;
  const int w = tid >> 6;
  const int g = lane >> 4;          // k-group within wave
  const int q = lane & 15;          // local q row (swapped layout)
  const int bh = blockIdx.x;
  const int b = bh >> 5, h = bh & 31, hkv = (bh & 31) >> 2;
  const size_t qbase = (size_t)(b * 32 + h) * 2048 * 64;
  const size_t kbase = (size_t)(b * 8 + hkv) * 2048 * 64;
  const size_t vbase = (size_t)(b * 8 + hkv) * 64 * 2048;
  const int pair = blockIdx.y;
  const int srcQ = (lane & 48) | (4 * g);   // +j : alpha/l redistribute source

  auto stageKV = [&](int k0, int buf) {
#pragma unroll
    for (int i = 0; i < 2; ++i) {
      int off = w * 2048 + i * 1024 + lane * 16;
      int sw2 = off ^ (((off >> 7) & 7) << 4);
      int r = sw2 >> 7, ce = (sw2 & 127) >> 1;
      gload_lds16(Kk + kbase + (size_t)(k0 + r) * 64 + ce,
                  (u16*)lds_k[buf] + ((w * 2048 + i * 1024) >> 1));
      gload_lds16(Vt + vbase + (size_t)r * 2048 + k0 + ce,
                  (u16*)lds_v[buf] + ((w * 2048 + i * 1024) >> 1));
    }
  };

  for (int half = 0; half < 2; ++half) {
    const int qt = half ? (31 - pair) : pair;
    const int qb = qt * 64;

    bf16x8 aq[2];
    {
      const u16* qp = Q + qbase + (size_t)(qb + w * 16 + q) * 64 + g * 8;
      aq[0] = *(const bf16x8*)(qp);
      aq[1] = *(const bf16x8*)(qp + 32);
    }

    f32x4 oacc[4] = {};
    float m = -1e30f, l = 0.f;

    stageKV(0, 0);

    for (int kt = 0; kt <= qt; ++kt) {
      const int cur = kt & 1;
      if (kt < qt) {
        stageKV((kt + 1) * 64, cur ^ 1);
        asm volatile("s_waitcnt vmcnt(4)" ::: "memory");
      } else {
        asm volatile("s_waitcnt vmcnt(0)" ::: "memory");
      }
      __builtin_amdgcn_s_barrier();
      asm volatile("" ::: "memory");

      const bool diag = (kt == qt);
      const int nmax = diag ? w : 3;        // subtiles n>w fully masked on diag

      // S^T = K Q^T per wave: sacc[n][j] = S[k = 16n+4g+j][q]
      f32x4 sacc[4] = {};
#pragma unroll
      for (int n = 0; n < 4; ++n) {
        if (n > nmax) break;
        int row = n * 16 + q;
#pragma unroll
        for (int c = 0; c < 2; ++c) {
          int byte = row * 128 + c * 64 + g * 16;
          byte ^= ((row & 7) << 4);
          bf16x8 ak = *(const bf16x8*)&lds_k[cur][byte >> 1];
          sacc[n] = __builtin_amdgcn_mfma_f32_16x16x32_bf16(ak, aq[c], sacc[n], 0, 0, 0);
        }
      }

      if (diag) {
#pragma unroll
        for (int n = 0; n < 4; ++n)
#pragma unroll
          for (int j = 0; j < 4; ++j)
            if (n * 16 + 4 * g + j > w * 16 + q) sacc[n][j] = -1e30f;
      }

      float mx = sacc[0][0];
#pragma unroll
      for (int n = 0; n < 4; ++n)
#pragma unroll
        for (int j = 0; j < 4; ++j) mx = fmaxf(mx, sacc[n][j]);
      mx = fmaxf(mx, __shfl_xor(mx, 16, 64));
      mx = fmaxf(mx, __shfl_xor(mx, 32, 64));
      float mnew = fmaxf(m, mx);
      float alpha = fexp2(m - mnew);
      m = mnew;

      float p[4][4];
      float rs = 0.f;
#pragma unroll
      for (int n = 0; n < 4; ++n)
#pragma unroll
        for (int j = 0; j < 4; ++j) {
          float pv = fexp2(sacc[n][j] - mnew);
          p[n][j] = pv;
          rs += pv;
        }
      rs += __shfl_xor(rs, 16, 64);
      rs += __shfl_xor(rs, 32, 64);
      l = l * alpha + rs;

#pragma unroll
      for (int j = 0; j < 4; ++j) {
        float aj = __shfl(alpha, srcQ + j, 64);
#pragma unroll
        for (int n = 0; n < 4; ++n) oacc[n][j] *= aj;
      }

      // pack P pairs and exchange via per-wave swizzled LDS (intra-wave only)
      unsigned pk[4][2];
#pragma unroll
      for (int n = 0; n < 4; ++n) {
        pk[n][0] = cvt_pk_bf16(p[n][0], p[n][1]);
        pk[n][1] = cvt_pk_bf16(p[n][2], p[n][3]);
      }
      {
        char* pbase = (char*)lds_p[w] + q * 128;
#pragma unroll
        for (int n = 0; n < 4; ++n) {
          unsigned long long v =
              (unsigned long long)pk[n][0] | ((unsigned long long)pk[n][1] << 32);
          // logical 16B slot u = 2n + (g>>1); physical slot = u ^ (q&7)
          *(unsigned long long*)(pbase + (((2 * n + (g >> 1)) ^ (q & 7)) << 4) +
                                 ((g & 1) << 3)) = v;
        }
      }

      // O += P V: A-frag = P[q][32c + 8g + 0..7] from swizzled slot (4c+g)^(q&7)
#pragma unroll
      for (int c = 0; c < 2; ++c) {
        if (diag && w < 2 && c == 1) break;   // k-chunk fully masked
        bf16x8 pa = *(const bf16x8*)((char*)lds_p[w] + q * 128 +
                                     (((4 * c + g) ^ (q & 7)) << 4));
#pragma unroll
        for (int n = 0; n < 4; ++n) {
          int row = n * 16 + q;
          int byte = row * 128 + c * 64 + g * 16;
          byte ^= ((row & 7) << 4);
          bf16x8 bv = *(const bf16x8*)&lds_v[cur][byte >> 1];
          oacc[n] = __builtin_amdgcn_mfma_f32_16x16x32_bf16(pa, bv, oacc[n], 0, 0, 0);
        }
      }
      __builtin_amdgcn_s_barrier();
    }

    // epilogue: O/l -> bf16, layout [b*2048+s][h*64+d]
    float linv[4];
#pragma unroll
    for (int j = 0; j < 4; ++j)
      linv[j] = __builtin_amdgcn_rcpf(__shfl(l, srcQ + j, 64));
#pragma unroll
    for (int n = 0; n < 4; ++n) {
      int col = h * 64 + n * 16 + q;
#pragma unroll
      for (int j = 0; j < 4; ++j) {
        int qrow = qb + w * 16 + 4 * g + j;
        O[(size_t)(b * 2048 + qrow) * 2048 + col] = f2bf(oacc[n][j] * linv[j]);
      }
    }
  }
}

// ---------------------------------------------------------------------------
extern "C" void kernel_launch(void* const* d_in, const int* in_sizes, int n_in,
                              void* d_out, int out_size, void* d_ws, size_t ws_size,
                              hipStream_t stream) {
  const float* hidden = (const float*)d_in[0];
  const int* pos = (const int*)d_in[1];
  // d_in[2] = attention_mask: exact causal mask, implemented analytically
  const float* qkv_w = (const float*)d_in[3];
  const float* o_w = (const float*)d_in[4];
  float* out = (float*)d_out;
  char* ws = (char*)d_ws;

  u16* wqkvT  = (u16*)(ws + 0);                 // [3072][2048] bf16, 12.6MB
  u16* woT    = (u16*)(ws + 12582912);          // [2048][2048] bf16, 8.4MB
  u16* hidb   = (u16*)(ws + 20971520);          // [4096][2048] bf16 (reused as Q)
  float* qkvbuf = (float*)(ws + 37748736);      // [4096][3072] f32 (reused as attn out)
  u16* kb     = (u16*)(ws + 88080384);          // [2][8][2048][64] bf16
  u16* vtb    = (u16*)(ws + 92274688);          // [2][8][64][2048] bf16
  float* cost = (float*)(ws + 96468992);        // [2048][32]
  float* sint = (float*)(ws + 96731136);
  u16* qbuf   = hidb;                            // alias: hidden_bf16 dead after GEMM1
  u16* attnb  = (u16*)qkvbuf;                    // alias: qkv_buf dead after scatter

  conv_bf16_kernel<<<4096, 256, 0, stream>>>(hidden, hidb, 1048576);
  wtrans_kernel<<<dim3(96, 64), 256, 0, stream>>>(qkv_w, wqkvT, 2048, 3072);
  wtrans_kernel<<<dim3(64, 64), 256, 0, stream>>>(o_w, woT, 2048, 2048);
  rope_table_kernel<<<256, 256, 0, stream>>>(cost, sint);

  gemm256_kernel<<<dim3(12, 16), 512, 0, stream>>>(hidb, wqkvT, qkvbuf, 4096, 3072, 2048);

  rope_scatter_kernel<<<4096, 256, 0, stream>>>(qkvbuf, pos, cost, sint, qbuf, kb);
  vtrans_kernel<<<dim3(16, 32), 256, 0, stream>>>(qkvbuf, vtb);

  attn_kernel<<<dim3(64, 16), 256, 0, stream>>>(qbuf, kb, vtb, attnb);

  gemm256_kernel<<<dim3(8, 16), 512, 0, stream>>>(attnb, woT, out, 4096, 2048, 2048);
}

// Round 6
// 357.633 us; speedup vs baseline: 1.2051x; 1.2051x over previous
//
#include <hip/hip_runtime.h>
#include <stdint.h>

// ---------------------------------------------------------------------------
// Phi3 attention block: QKV GEMM -> RoPE -> flash attn (causal, GQA) -> O GEMM
// B=2, S=2048, HID=2048, Hq=32, Hkv=8, D=64. fp32 in/out, bf16 MFMA inside.
// Round 5 (resubmit; round-5 bench was a GPU-broker timeout, kernel never ran):
// GEMM fix — BM=256,BN=128,BK=64, 8 waves (4Mx2N), proper (row&7)<<4 LDS
// swizzle (round-4's bit9 swizzle caused 9.4M conflicts), grids 384/256
// blocks (round-4's 192/128 left half the chip idle). Attn/aux unchanged.
// ---------------------------------------------------------------------------

typedef unsigned short u16;
typedef __bf16 bf16x8 __attribute__((ext_vector_type(8)));
typedef float f32x4 __attribute__((ext_vector_type(4)));
typedef unsigned short u16x8 __attribute__((ext_vector_type(8)));

__device__ __forceinline__ u16 f2bf(float f) {
  unsigned int u = __float_as_uint(f);
  u += 0x7fffu + ((u >> 16) & 1u);   // RNE
  return (u16)(u >> 16);
}

__device__ __forceinline__ unsigned cvt_pk_bf16(float lo, float hi) {
  unsigned r;
  asm("v_cvt_pk_bf16_f32 %0, %1, %2" : "=v"(r) : "v"(lo), "v"(hi));
  return r;
}

__device__ __forceinline__ float fexp2(float x) {
  float r;
  asm("v_exp_f32 %0, %1" : "=v"(r) : "v"(x));
  return r;
}

__device__ __forceinline__ void gload_lds16(const void* g, void* l) {
  __builtin_amdgcn_global_load_lds((const __attribute__((address_space(1))) void*)g,
                                   (__attribute__((address_space(3))) void*)l, 16, 0, 0);
}

// --------------------------- fp32 -> bf16 flat copy -------------------------
__global__ __launch_bounds__(256) void conv_bf16_kernel(const float* __restrict__ in,
                                                        u16* __restrict__ out, int n8) {
  int i = blockIdx.x * 256 + threadIdx.x;
  int stride = gridDim.x * 256;
  for (; i < n8; i += stride) {
    const float4* p = (const float4*)in + (size_t)i * 2;
    float4 a = p[0], b = p[1];
    u16x8 o;
    o[0] = f2bf(a.x); o[1] = f2bf(a.y); o[2] = f2bf(a.z); o[3] = f2bf(a.w);
    o[4] = f2bf(b.x); o[5] = f2bf(b.y); o[6] = f2bf(b.z); o[7] = f2bf(b.w);
    *(u16x8*)(out + (size_t)i * 8) = o;
  }
}

// --------------------- fp32 [R][C] -> bf16 transposed [C][R] ----------------
__global__ __launch_bounds__(256) void wtrans_kernel(const float* __restrict__ in,
                                                     u16* __restrict__ out, int R, int C) {
  __shared__ float tile[32][33];
  int tx = threadIdx.x & 31, ty = threadIdx.x >> 5;   // 32x8
  int col = blockIdx.x * 32 + tx;
  for (int j = ty; j < 32; j += 8)
    tile[j][tx] = in[(size_t)(blockIdx.y * 32 + j) * C + col];
  __syncthreads();
  int ocol = blockIdx.y * 32 + tx;                    // out col = in row
  for (int j = ty; j < 32; j += 8)
    out[(size_t)(blockIdx.x * 32 + j) * R + ocol] = f2bf(tile[tx][j]);
}

// ----------------------------- cos/sin tables -------------------------------
__global__ __launch_bounds__(256) void rope_table_kernel(float* __restrict__ cost,
                                                         float* __restrict__ sint) {
  int idx = blockIdx.x * 256 + threadIdx.x;           // 2048*32
  if (idx >= 2048 * 32) return;
  int p = idx >> 5, i = idx & 31;
  float invf = powf(10000.f, -(float)i / 32.f);
  float ang = (float)p * invf;
  cost[idx] = cosf(ang);
  sint[idx] = sinf(ang);
}

// ------------------ 256x128 2-phase bf16 GEMM, B transposed -----------------
// C[M][N] f32 = A[M][K] * Bt[N][K]^T. BK=64, 512 thr = 8 waves (4M x 2N),
// per-wave 64x64 out (4x4 frags). LDS 96KB: 2 bufs x (A 32KB + B 16KB).
// Swizzle: phys_byte = logical ^ ((row&7)<<4) on stage-source AND reads
// (128B rows -> 8-slot spread, residual 2-way free). Per K-tile: 2 phases of
// {8 ds_read_b128; [stage next tile]; barrier; setprio+16 MFMA; barrier},
// vmcnt(0) once per tile before the swap barrier. XCD-bijective block swizzle.
__global__ __launch_bounds__(512) void gemm256_kernel(const u16* __restrict__ A,
                                                      const u16* __restrict__ Bt,
                                                      float* __restrict__ C,
                                                      int M, int N, int K) {
  __shared__ __align__(16) char lds[98304];
  const int tid = threadIdx.x;
  const int lane = tid & 63;
  const int w = tid >> 6;
  const int wm = w >> 1, wn = w & 1;
  const int g = lane >> 4, lq = lane & 15;

  // XCD-aware bijective block swizzle (nwg % 8 == 0 for all our grids)
  const int nwg = gridDim.x * gridDim.y;
  const int flat = blockIdx.y * gridDim.x + blockIdx.x;
  const int cpx = nwg >> 3;
  const int swb = (flat & 7) * cpx + (flat >> 3);
  const int bx = swb % gridDim.x, by = swb / gridDim.x;
  const int brow = by * 256, bcol = bx * 128;

  f32x4 acc[4][4] = {};

  auto stageA = [&](int kt, int buf) {
    char* ab = lds + buf * 49152;
#pragma unroll
    for (int i = 0; i < 4; ++i) {
      int D = (w * 4 + i) * 1024 + lane * 16;   // linear dest byte in 32KB tile
      int r = D >> 7;                           // row (128B rows)
      int L = D ^ ((r & 7) << 4);               // logical byte (involution)
      int ce = (L & 127) >> 1;                  // element within row
      gload_lds16(A + (size_t)(brow + r) * K + kt + ce, ab + D);
    }
  };
  auto stageB = [&](int kt, int buf) {
    char* bb = lds + buf * 49152 + 32768;
#pragma unroll
    for (int i = 0; i < 2; ++i) {
      int D = (w * 2 + i) * 1024 + lane * 16;
      int r = D >> 7;
      int L = D ^ ((r & 7) << 4);
      int ce = (L & 127) >> 1;
      gload_lds16(Bt + (size_t)(bcol + r) * K + kt + ce, bb + D);
    }
  };

  stageA(0, 0);
  stageB(0, 0);
  asm volatile("s_waitcnt vmcnt(0)" ::: "memory");
  __builtin_amdgcn_s_barrier();
  asm volatile("" ::: "memory");

  const int nt = K >> 6;
  for (int t = 0; t < nt; ++t) {
    const int cur = t & 1;
    const char* ab = lds + cur * 49152;
    const char* bb = ab + 32768;

#pragma unroll
    for (int kk = 0; kk < 2; ++kk) {
      bf16x8 af[4], bfr[4];
#pragma unroll
      for (int fm = 0; fm < 4; ++fm) {
        int r = wm * 64 + fm * 16 + lq;
        int lin = r * 128 + kk * 64 + g * 16;
        af[fm] = *(const bf16x8*)(ab + (lin ^ ((r & 7) << 4)));
      }
#pragma unroll
      for (int fn = 0; fn < 4; ++fn) {
        int r = wn * 64 + fn * 16 + lq;
        int lin = r * 128 + kk * 64 + g * 16;
        bfr[fn] = *(const bf16x8*)(bb + (lin ^ ((r & 7) << 4)));
      }
      if (kk == 0 && t + 1 < nt) {
        stageA((t + 1) << 6, cur ^ 1);
        stageB((t + 1) << 6, cur ^ 1);
      }
      __builtin_amdgcn_s_barrier();
      asm volatile("" ::: "memory");
      __builtin_amdgcn_s_setprio(1);
#pragma unroll
      for (int fm = 0; fm < 4; ++fm)
#pragma unroll
        for (int fn = 0; fn < 4; ++fn)
          acc[fm][fn] = __builtin_amdgcn_mfma_f32_16x16x32_bf16(
              af[fm], bfr[fn], acc[fm][fn], 0, 0, 0);
      __builtin_amdgcn_s_setprio(0);
      if (kk == 1 && t + 1 < nt)
        asm volatile("s_waitcnt vmcnt(0)" ::: "memory");   // next tile staged
      __builtin_amdgcn_s_barrier();
      asm volatile("" ::: "memory");
    }
  }

#pragma unroll
  for (int fm = 0; fm < 4; ++fm) {
    int row0 = brow + wm * 64 + fm * 16 + g * 4;
#pragma unroll
    for (int fn = 0; fn < 4; ++fn) {
      int col = bcol + wn * 64 + fn * 16 + lq;
#pragma unroll
      for (int j = 0; j < 4; ++j)
        C[(size_t)(row0 + j) * N + col] = acc[fm][fn][j];
    }
  }
}

// ------------------- RoPE + scatter q/k into head-major bf16 ----------------
// qkv fp32 [4096][3072] -> Q bf16 [B,32,S,64] (scaled by log2e/8), K bf16 [B,8,S,64]
__global__ __launch_bounds__(256) void rope_scatter_kernel(const float* __restrict__ qkv,
                                                           const int* __restrict__ pos_ids,
                                                           const float* __restrict__ cost,
                                                           const float* __restrict__ sint,
                                                           u16* __restrict__ Qo,
                                                           u16* __restrict__ Ko) {
  int t = blockIdx.x;                 // token 0..4095
  int b = t >> 11, s = t & 2047;
  int pos = pos_ids[t];
  const float* row = qkv + (size_t)t * 3072;
  int tid = threadIdx.x;
  const float QSCALE = 0.125f * 1.44269504088896340736f;  // 1/sqrt(64) * log2(e)

  for (int idx = tid; idx < 1024; idx += 256) {
    int hh = idx >> 5, i = idx & 31;
    float x1 = row[hh * 64 + i], x2 = row[hh * 64 + i + 32];
    float c = cost[pos * 32 + i], sn = sint[pos * 32 + i];
    float o1 = (x1 * c - x2 * sn) * QSCALE;
    float o2 = (x2 * c + x1 * sn) * QSCALE;
    size_t base = ((size_t)(b * 32 + hh) * 2048 + s) * 64;
    Qo[base + i] = f2bf(o1);
    Qo[base + i + 32] = f2bf(o2);
  }
  {
    int hh = tid >> 5, i = tid & 31;
    float x1 = row[2048 + hh * 64 + i], x2 = row[2048 + hh * 64 + i + 32];
    float c = cost[pos * 32 + i], sn = sint[pos * 32 + i];
    float o1 = x1 * c - x2 * sn;
    float o2 = x2 * c + x1 * sn;
    size_t base = ((size_t)(b * 8 + hh) * 2048 + s) * 64;
    Ko[base + i] = f2bf(o1);
    Ko[base + i + 32] = f2bf(o2);
  }
}

// ---------------- V: qkv fp32 cols [2560,3072) -> Vt bf16 [B,8,64,S] --------
__global__ __launch_bounds__(256) void vtrans_kernel(const float* __restrict__ qkv,
                                                     u16* __restrict__ Vt) {
  __shared__ float tile[64][65];
  int b = blockIdx.x >> 3, hv = blockIdx.x & 7;
  int s0 = blockIdx.y * 64;
  int tid = threadIdx.x;
  for (int idx = tid; idx < 4096; idx += 256) {
    int tok = idx >> 6, c = idx & 63;
    tile[tok][c] = qkv[(size_t)(b * 2048 + s0 + tok) * 3072 + 2560 + hv * 64 + c];
  }
  __syncthreads();
  size_t obase = (size_t)(b * 8 + hv) * 64 * 2048;
  for (int idx = tid; idx < 4096; idx += 256) {
    int d = idx >> 6, si = idx & 63;
    Vt[obase + (size_t)d * 2048 + s0 + si] = f2bf(tile[si][d]);
  }
}

// ------------------------------- flash attention ----------------------------
// grid (B*H=64, 16 pairs). Block = 4 waves; q-tiles {pair, 31-pair} -> 33
// balanced iters. Swapped QK^T (S^T: lane&15 = q). Double-buffered K/V LDS
// with counted vmcnt(4); per-wave swizzled LDS P-exchange; raw v_exp_f32.
__global__ __launch_bounds__(256) void attn_kernel(const u16* __restrict__ Q,
                                                   const u16* __restrict__ Kk,
                                                   const u16* __restrict__ Vt,
                                                   u16* __restrict__ O) {
  __shared__ __align__(16) u16 lds_k[2][64 * 64];
  __shared__ __align__(16) u16 lds_v[2][64 * 64];
  __shared__ __align__(16) u16 lds_p[4][1024];   // per-wave 2KB, 16B-slot swizzled

  const int tid = threadIdx.x;
  const int lane = tid & 63;
  const int w = tid >> 6;
  const int g = lane >> 4;          // k-group within wave
  const int q = lane & 15;          // local q row (swapped layout)
  const int bh = blockIdx.x;
  const int b = bh >> 5, h = bh & 31, hkv = (bh & 31) >> 2;
  const size_t qbase = (size_t)(b * 32 + h) * 2048 * 64;
  const size_t kbase = (size_t)(b * 8 + hkv) * 2048 * 64;
  const size_t vbase = (size_t)(b * 8 + hkv) * 64 * 2048;
  const int pair = blockIdx.y;
  const int srcQ = (lane & 48) | (4 * g);   // +j : alpha/l redistribute source

  auto stageKV = [&](int k0, int buf) {
#pragma unroll
    for (int i = 0; i < 2; ++i) {
      int off = w * 2048 + i * 1024 + lane * 16;
      int sw2 = off ^ (((off >> 7) & 7) << 4);
      int r = sw2 >> 7, ce = (sw2 & 127) >> 1;
      gload_lds16(Kk + kbase + (size_t)(k0 + r) * 64 + ce,
                  (u16*)lds_k[buf] + ((w * 2048 + i * 1024) >> 1));
      gload_lds16(Vt + vbase + (size_t)r * 2048 + k0 + ce,
                  (u16*)lds_v[buf] + ((w * 2048 + i * 1024) >> 1));
    }
  };

  for (int half = 0; half < 2; ++half) {
    const int qt = half ? (31 - pair) : pair;
    const int qb = qt * 64;

    bf16x8 aq[2];
    {
      const u16* qp = Q + qbase + (size_t)(qb + w * 16 + q) * 64 + g * 8;
      aq[0] = *(const bf16x8*)(qp);
      aq[1] = *(const bf16x8*)(qp + 32);
    }

    f32x4 oacc[4] = {};
    float m = -1e30f, l = 0.f;

    stageKV(0, 0);

    for (int kt = 0; kt <= qt; ++kt) {
      const int cur = kt & 1;
      if (kt < qt) {
        stageKV((kt + 1) * 64, cur ^ 1);
        asm volatile("s_waitcnt vmcnt(4)" ::: "memory");
      } else {
        asm volatile("s_waitcnt vmcnt(0)" ::: "memory");
      }
      __builtin_amdgcn_s_barrier();
      asm volatile("" ::: "memory");

      const bool diag = (kt == qt);
      const int nmax = diag ? w : 3;        // subtiles n>w fully masked on diag

      // S^T = K Q^T per wave: sacc[n][j] = S[k = 16n+4g+j][q]
      f32x4 sacc[4] = {};
#pragma unroll
      for (int n = 0; n < 4; ++n) {
        if (n > nmax) break;
        int row = n * 16 + q;
#pragma unroll
        for (int c = 0; c < 2; ++c) {
          int byte = row * 128 + c * 64 + g * 16;
          byte ^= ((row & 7) << 4);
          bf16x8 ak = *(const bf16x8*)&lds_k[cur][byte >> 1];
          sacc[n] = __builtin_amdgcn_mfma_f32_16x16x32_bf16(ak, aq[c], sacc[n], 0, 0, 0);
        }
      }

      if (diag) {
#pragma unroll
        for (int n = 0; n < 4; ++n)
#pragma unroll
          for (int j = 0; j < 4; ++j)
            if (n * 16 + 4 * g + j > w * 16 + q) sacc[n][j] = -1e30f;
      }

      float mx = sacc[0][0];
#pragma unroll
      for (int n = 0; n < 4; ++n)
#pragma unroll
        for (int j = 0; j < 4; ++j) mx = fmaxf(mx, sacc[n][j]);
      mx = fmaxf(mx, __shfl_xor(mx, 16, 64));
      mx = fmaxf(mx, __shfl_xor(mx, 32, 64));
      float mnew = fmaxf(m, mx);
      float alpha = fexp2(m - mnew);
      m = mnew;

      float p[4][4];
      float rs = 0.f;
#pragma unroll
      for (int n = 0; n < 4; ++n)
#pragma unroll
        for (int j = 0; j < 4; ++j) {
          float pv = fexp2(sacc[n][j] - mnew);
          p[n][j] = pv;
          rs += pv;
        }
      rs += __shfl_xor(rs, 16, 64);
      rs += __shfl_xor(rs, 32, 64);
      l = l * alpha + rs;

#pragma unroll
      for (int j = 0; j < 4; ++j) {
        float aj = __shfl(alpha, srcQ + j, 64);
#pragma unroll
        for (int n = 0; n < 4; ++n) oacc[n][j] *= aj;
      }

      // pack P pairs and exchange via per-wave swizzled LDS (intra-wave only)
      unsigned pk[4][2];
#pragma unroll
      for (int n = 0; n < 4; ++n) {
        pk[n][0] = cvt_pk_bf16(p[n][0], p[n][1]);
        pk[n][1] = cvt_pk_bf16(p[n][2], p[n][3]);
      }
      {
        char* pbase = (char*)lds_p[w] + q * 128;
#pragma unroll
        for (int n = 0; n < 4; ++n) {
          unsigned long long v =
              (unsigned long long)pk[n][0] | ((unsigned long long)pk[n][1] << 32);
          // logical 16B slot u = 2n + (g>>1); physical slot = u ^ (q&7)
          *(unsigned long long*)(pbase + (((2 * n + (g >> 1)) ^ (q & 7)) << 4) +
                                 ((g & 1) << 3)) = v;
        }
      }

      // O += P V: A-frag = P[q][32c + 8g + 0..7] from swizzled slot (4c+g)^(q&7)
#pragma unroll
      for (int c = 0; c < 2; ++c) {
        if (diag && w < 2 && c == 1) break;   // k-chunk fully masked
        bf16x8 pa = *(const bf16x8*)((char*)lds_p[w] + q * 128 +
                                     (((4 * c + g) ^ (q & 7)) << 4));
#pragma unroll
        for (int n = 0; n < 4; ++n) {
          int row = n * 16 + q;
          int byte = row * 128 + c * 64 + g * 16;
          byte ^= ((row & 7) << 4);
          bf16x8 bv = *(const bf16x8*)&lds_v[cur][byte >> 1];
          oacc[n] = __builtin_amdgcn_mfma_f32_16x16x32_bf16(pa, bv, oacc[n], 0, 0, 0);
        }
      }
      __builtin_amdgcn_s_barrier();
    }

    // epilogue: O/l -> bf16, layout [b*2048+s][h*64+d]
    float linv[4];
#pragma unroll
    for (int j = 0; j < 4; ++j)
      linv[j] = __builtin_amdgcn_rcpf(__shfl(l, srcQ + j, 64));
#pragma unroll
    for (int n = 0; n < 4; ++n) {
      int col = h * 64 + n * 16 + q;
#pragma unroll
      for (int j = 0; j < 4; ++j) {
        int qrow = qb + w * 16 + 4 * g + j;
        O[(size_t)(b * 2048 + qrow) * 2048 + col] = f2bf(oacc[n][j] * linv[j]);
      }
    }
  }
}

// ---------------------------------------------------------------------------
extern "C" void kernel_launch(void* const* d_in, const int* in_sizes, int n_in,
                              void* d_out, int out_size, void* d_ws, size_t ws_size,
                              hipStream_t stream) {
  const float* hidden = (const float*)d_in[0];
  const int* pos = (const int*)d_in[1];
  // d_in[2] = attention_mask: exact causal mask, implemented analytically
  const float* qkv_w = (const float*)d_in[3];
  const float* o_w = (const float*)d_in[4];
  float* out = (float*)d_out;
  char* ws = (char*)d_ws;

  u16* wqkvT  = (u16*)(ws + 0);                 // [3072][2048] bf16, 12.6MB
  u16* woT    = (u16*)(ws + 12582912);          // [2048][2048] bf16, 8.4MB
  u16* hidb   = (u16*)(ws + 20971520);          // [4096][2048] bf16 (reused as Q)
  float* qkvbuf = (float*)(ws + 37748736);      // [4096][3072] f32 (reused as attn out)
  u16* kb     = (u16*)(ws + 88080384);          // [2][8][2048][64] bf16
  u16* vtb    = (u16*)(ws + 92274688);          // [2][8][64][2048] bf16
  float* cost = (float*)(ws + 96468992);        // [2048][32]
  float* sint = (float*)(ws + 96731136);
  u16* qbuf   = hidb;                            // alias: hidden_bf16 dead after GEMM1
  u16* attnb  = (u16*)qkvbuf;                    // alias: qkv_buf dead after scatter

  conv_bf16_kernel<<<4096, 256, 0, stream>>>(hidden, hidb, 1048576);
  wtrans_kernel<<<dim3(96, 64), 256, 0, stream>>>(qkv_w, wqkvT, 2048, 3072);
  wtrans_kernel<<<dim3(64, 64), 256, 0, stream>>>(o_w, woT, 2048, 2048);
  rope_table_kernel<<<256, 256, 0, stream>>>(cost, sint);

  gemm256_kernel<<<dim3(24, 16), 512, 0, stream>>>(hidb, wqkvT, qkvbuf, 4096, 3072, 2048);

  rope_scatter_kernel<<<4096, 256, 0, stream>>>(qkvbuf, pos, cost, sint, qbuf, kb);
  vtrans_kernel<<<dim3(16, 32), 256, 0, stream>>>(qkvbuf, vtb);

  attn_kernel<<<dim3(64, 16), 256, 0, stream>>>(qbuf, kb, vtb, attnb);

  gemm256_kernel<<<dim3(16, 16), 512, 0, stream>>>(attnb, woT, out, 4096, 2048, 2048);
}